// Round 5
// baseline (793.073 us; speedup 1.0000x reference)
//
#include <hip/hip_runtime.h>
#include <hip/hip_bf16.h>

typedef short s16x8 __attribute__((ext_vector_type(8)));
typedef float f32x4 __attribute__((ext_vector_type(4)));

namespace {
constexpr int kB   = 8;
constexpr int kN   = 5000;
constexpr int kE   = 40000;
constexpr int kF   = 64;
constexpr int kFE  = 16;
constexpr int kFil = 96;
constexpr float kEps = 1e-3f;
constexpr int kBN = kB * kN;   // 40000
constexpr int kBE = kB * kE;   // 320000
constexpr int kKp = 160;       // padded K (msg 144->160, upd exact 160)
constexpr int kLd = 184;       // LDS row stride (bf16): 368B -> 16 distinct banks/row
constexpr int kBM = 128;       // rows per block
constexpr int kTS = 49;        // sT row stride in u32 (48 pairs + 1 pad)
}

// float -> bf16 (RNE) bit-twiddle — kept only for the tiny prep kernel
__device__ inline unsigned short f2bf(float x) {
    unsigned u = __float_as_uint(x);
    u += 0x7FFFu + ((u >> 16) & 1u);
    return (unsigned short)(u >> 16);
}

// 8x fp32 -> 8x bf16 via v_cvt_pk_bf16_f32 (RNE)
__device__ inline s16x8 pack8(const float4& a, const float4& b) {
    union { s16x8 s; __hip_bfloat162 h[4]; } r;
    r.h[0] = __float22bfloat162_rn(make_float2(a.x, a.y));
    r.h[1] = __float22bfloat162_rn(make_float2(a.z, a.w));
    r.h[2] = __float22bfloat162_rn(make_float2(b.x, b.y));
    r.h[3] = __float22bfloat162_rn(make_float2(b.z, b.w));
    return r.s;
}

// Load 8 consecutive fp32 (16B-aligned) -> bf16x8 A-fragment
__device__ inline s16x8 loadA8(const float* __restrict__ p) {
    const float4* q = reinterpret_cast<const float4*>(p);
    return pack8(q[0], q[1]);
}

// ---------------------------------------------------------------------------
// Prep: W (K,96) fp32 -> WT (96,Kp) bf16, zero-padded K rows. Runs once/call.
// ---------------------------------------------------------------------------
__global__ void prep_wT(const float* __restrict__ Wm, const float* __restrict__ Wu,
                        short* __restrict__ wmT, short* __restrict__ wuT) {
    const int t = blockIdx.x * 256 + threadIdx.x;
    if (t >= 96 * kKp) return;
    const int n = t / kKp, k = t % kKp;
    wmT[t] = (k < 144) ? (short)f2bf(Wm[(size_t)k * 96 + n]) : (short)0;
    wuT[t] = (short)f2bf(Wu[(size_t)k * 96 + n]);
}

// ---------------------------------------------------------------------------
// Shared MFMA GEMM + fp32 bias/ReLU/LN epilogue + store (+fused atomic agg).
// A-frags in registers; B-frags from LDS. C/D: col=lane&15, row=quad*4+reg.
// LN: row lives in one 16-lane quad across 6 N-tiles -> shfl_xor(1,2,4,8).
// out stores: lane-paired float2 (12 wave-instrs instead of 24).
// Fused agg (msg only): pk-bf16 pairs staged to a per-wave LDS tile sTw
// (no barrier needed — single-wave visibility), then drained as 12
// FULLY LANE-DENSE global_atomic_pk_add_bf16 instructions (was 24
// half-dense) — attacks the per-VMEM-instruction issue wall.
// ---------------------------------------------------------------------------
__device__ inline void gemm_ln_store(const s16x8 a[5], const short* sB,
                                     const float* __restrict__ bias,
                                     const float* __restrict__ gamma_,
                                     const float* __restrict__ beta_,
                                     float* __restrict__ out,
                                     const int* __restrict__ edges2,  // msg only
                                     short* __restrict__ aggOut,      // msg only (bf16)
                                     unsigned* __restrict__ sTw,      // msg only: [16][kTS]
                                     int rowBase, int rowMax) {
    const int tid  = threadIdx.x;
    const int w    = tid >> 6;
    const int lane = tid & 63;
    const int cl   = lane & 15;
    const int quad = lane >> 4;

    f32x4 acc[6] = {};
#pragma unroll
    for (int ks = 0; ks < 5; ++ks) {
#pragma unroll
        for (int t = 0; t < 6; ++t) {
            s16x8 b = *reinterpret_cast<const s16x8*>(
                sB + (16 * t + cl) * kLd + ks * 32 + quad * 8);
            acc[t] = __builtin_amdgcn_mfma_f32_16x16x32_bf16(a[ks], b, acc[t], 0, 0, 0);
        }
    }

    float bmv[6], gv[6], bv[6];
#pragma unroll
    for (int t = 0; t < 6; ++t) {
        const int c = 16 * t + cl;
        bmv[t] = bias[c]; gv[t] = gamma_[c]; bv[t] = beta_[c];
    }
#pragma unroll
    for (int j = 0; j < 4; ++j) {
        float v0[6];
        float s = 0.f;
#pragma unroll
        for (int t = 0; t < 6; ++t) {
            v0[t] = fmaxf(acc[t][j] + bmv[t], 0.f);
            s += v0[t];
        }
        s += __shfl_xor(s, 1); s += __shfl_xor(s, 2);
        s += __shfl_xor(s, 4); s += __shfl_xor(s, 8);
        const float mu = s * (1.f / 96.f);
        float q = 0.f;
#pragma unroll
        for (int t = 0; t < 6; ++t) {
            const float d = v0[t] - mu;
            q = fmaf(d, d, q);
        }
        q += __shfl_xor(q, 1); q += __shfl_xor(q, 2);
        q += __shfl_xor(q, 4); q += __shfl_xor(q, 8);
        const float inv = rsqrtf(q * (1.f / 96.f) + kEps);
        const int row = rowBase + 16 * w + 4 * quad + j;
        if (row < rowMax) {
            float ov[6];
#pragma unroll
            for (int t = 0; t < 6; ++t)
                ov[t] = (v0[t] - mu) * inv * gv[t] + bv[t];
            float* orow = out + (size_t)row * kFil;
#pragma unroll
            for (int t = 0; t < 6; ++t) {
                const float other = __shfl_xor(ov[t], 1);  // partner col, same row
                if ((cl & 1) == 0) {
                    // paired f32 store: cols (c, c+1), 8B aligned
                    float2 st; st.x = ov[t]; st.y = other;
                    *reinterpret_cast<float2*>(orow + 16 * t + cl) = st;
                    if (aggOut) {
                        __hip_bfloat162 hv =
                            __float22bfloat162_rn(make_float2(ov[t], other));
                        unsigned dw;
                        __builtin_memcpy(&dw, &hv, 4);
                        sTw[(4 * quad + j) * kTS + 8 * t + (cl >> 1)] = dw;
                    }
                }
            }
        }
    }

    if (aggOut) {
        // Drain: 12 fully lane-dense pk atomics. lane -> (row r = lane>>2,
        // pair p = (lane&3)*12 + i). Grid is exact for msg (no row guard).
        const int r    = lane >> 2;
        const int edge = rowBase + 16 * w + r;
        const int ob   = edge / kE;                      // magic-mul div
        const int dn   = edges2[(size_t)edge * 2 + 1];   // L1-hot
        short* arow = aggOut + ((size_t)ob * kN + dn) * kFil;
#pragma unroll
        for (int i = 0; i < 12; ++i) {
            const int p = (lane & 3) * 12 + i;
            const unsigned dw = sTw[r * kTS + p];
            asm volatile("global_atomic_pk_add_bf16 %0, %1, off"
                         :: "v"((unsigned long long)(arow + 2 * p)), "v"(dw)
                         : "memory");
        }
    }
}

// ---------------------------------------------------------------------------
// Message layer (MFMA): block = 128 edges, 8 waves, each wave owns 16 rows.
// A-fragments loaded directly from global (nodes/efeat are L2-hot).
// ---------------------------------------------------------------------------
__global__ __launch_bounds__(512, 4) void msg_mfma(
    const float* __restrict__ nodes, const float* __restrict__ efeat,
    const int* __restrict__ edges, const short* __restrict__ wmT,
    const float* __restrict__ bm, const float* __restrict__ g,
    const float* __restrict__ be, float* __restrict__ out_msg,
    short* __restrict__ agg) {
    __shared__ short sB[96 * kLd];            // 35328 B
    __shared__ unsigned sT[8][16 * kTS];      // 25088 B (per-wave pk-pair tiles)
    const int tid  = threadIdx.x;
    const int w    = tid >> 6;
    const int lane = tid & 63;
    const int cl   = lane & 15;
    const int quad = lane >> 4;

    const int row = blockIdx.x * kBM + 16 * w + cl;   // 2500*128 = 320000 exact
    const int b   = row / kE;
    const int2 e2 = reinterpret_cast<const int2*>(edges)[row];
    const float* srcp = nodes + ((size_t)b * kN + e2.x) * kF + 8 * quad;
    const float* dstp = nodes + ((size_t)b * kN + e2.y) * kF + 8 * quad;

    s16x8 a[5];
    a[0] = loadA8(srcp);           // k =   0+8q+j
    a[1] = loadA8(srcp + 32);      // k =  32+8q+j
    a[2] = loadA8(dstp);           // k =  64+8q+j
    a[3] = loadA8(dstp + 32);      // k =  96+8q+j
    if (quad < 2) {
        a[4] = loadA8(efeat + (size_t)row * kFE + 8 * quad);  // k = 128..143
    } else {
        s16x8 z = {};
        a[4] = z;                  // zero-pad K 144..159
    }

    for (int i = tid; i < 96 * kKp / 8; i += 512) {   // 1920 16B chunks
        const int n = i / 20, c = i % 20;
        *reinterpret_cast<s16x8*>(sB + n * kLd + 8 * c) =
            *reinterpret_cast<const s16x8*>(wmT + n * kKp + 8 * c);
    }
    __syncthreads();
    gemm_ln_store(a, sB, bm, g, be, out_msg, edges, agg, sT[w],
                  blockIdx.x * kBM, kBE);
}

// ---------------------------------------------------------------------------
// Update layer (MFMA): block = 128 nodes; X row = [node(64)|agg(96)], K=160.
// agg is bf16 -> A-fragments for k>=64 are direct 16B loads (no convert).
// ---------------------------------------------------------------------------
__global__ __launch_bounds__(512, 4) void upd_mfma(
    const float* __restrict__ nodes, const short* __restrict__ agg,
    const short* __restrict__ wuT, const float* __restrict__ bu,
    const float* __restrict__ g, const float* __restrict__ be,
    float* __restrict__ out_upd) {
    __shared__ short sB[96 * kLd];
    const int tid  = threadIdx.x;
    const int w    = tid >> 6;
    const int lane = tid & 63;
    const int cl   = lane & 15;
    const int quad = lane >> 4;

    const int node0 = blockIdx.x * kBM + 16 * w + cl;
    const int node  = (node0 < kBN) ? node0 : (kBN - 1);  // clamp loads; store guarded
    const float* np = nodes + (size_t)node * kF + 8 * quad;
    const short* ap = agg + (size_t)node * kFil;

    s16x8 a[5];
    a[0] = loadA8(np);                 // k =   0+8q+j -> node[ 0+8q..]
    a[1] = loadA8(np + 32);            // k =  32+8q+j -> node[32+8q..]
    a[2] = *reinterpret_cast<const s16x8*>(ap + 8 * quad);       // agg[ 0+8q..]
    a[3] = *reinterpret_cast<const s16x8*>(ap + 32 + 8 * quad);  // agg[32+8q..]
    a[4] = *reinterpret_cast<const s16x8*>(ap + 64 + 8 * quad);  // agg[64+8q..]

    for (int i = tid; i < 96 * kKp / 8; i += 512) {
        const int n = i / 20, c = i % 20;
        *reinterpret_cast<s16x8*>(sB + n * kLd + 8 * c) =
            *reinterpret_cast<const s16x8*>(wuT + n * kKp + 8 * c);
    }
    __syncthreads();
    gemm_ln_store(a, sB, bu, g, be, out_upd, nullptr, nullptr, nullptr,
                  blockIdx.x * kBM, kBN);
}

extern "C" void kernel_launch(void* const* d_in, const int* in_sizes, int n_in,
                              void* d_out, int out_size, void* d_ws, size_t ws_size,
                              hipStream_t stream) {
    const float* nodes  = (const float*)d_in[0];
    const float* efeat  = (const float*)d_in[1];
    const int*   edges  = (const int*)d_in[2];
    const float* Wm     = (const float*)d_in[3];
    const float* bm     = (const float*)d_in[4];
    const float* ln_m_g = (const float*)d_in[5];
    const float* ln_m_b = (const float*)d_in[6];
    const float* Wu     = (const float*)d_in[7];
    const float* bu     = (const float*)d_in[8];
    const float* ln_u_g = (const float*)d_in[9];
    const float* ln_u_b = (const float*)d_in[10];

    float* out_upd = (float*)d_out;                           // (B,N,96) first
    float* out_msg = (float*)d_out + (size_t)kBN * kFil;      // (B,E,96) second

    // workspace layout; 16B-aligned segments
    short* wmT = (short*)d_ws;                                // 96*160 bf16
    short* wuT = wmT + 96 * kKp;                              // 96*160 bf16
    short* agg = wuT + 96 * kKp;                              // B*N*96 bf16 (7.7 MB)

    // zero the aggregation buffer (atomic accumulation target)
    hipMemsetAsync(agg, 0, (size_t)kBN * kFil * sizeof(short), stream);
    prep_wT<<<(96 * kKp + 255) / 256, 256, 0, stream>>>(Wm, Wu, wmT, wuT);

    msg_mfma<<<kBE / kBM, 512, 0, stream>>>(
        nodes, efeat, edges, wmT, bm, ln_m_g, ln_m_b, out_msg, agg);
    upd_mfma<<<(kBN + kBM - 1) / kBM, 512, 0, stream>>>(
        nodes, agg, wuT, bu, ln_u_g, ln_u_b, out_upd);
}

// Round 6
// 275.987 us; speedup vs baseline: 2.8736x; 2.8736x over previous
//
#include <hip/hip_runtime.h>
#include <hip/hip_bf16.h>

typedef short s16x8 __attribute__((ext_vector_type(8)));
typedef float f32x4 __attribute__((ext_vector_type(4)));

namespace {
constexpr int kB   = 8;
constexpr int kN   = 5000;
constexpr int kE   = 40000;
constexpr int kF   = 64;
constexpr int kFE  = 16;
constexpr int kFil = 96;
constexpr float kEps = 1e-3f;
constexpr int kBN = kB * kN;   // 40000
constexpr int kBE = kB * kE;   // 320000
constexpr int kKp = 160;       // padded K (msg 144->160, upd exact 160)
constexpr int kLd = 168;       // LDS row stride in bf16 elems (r3-proven)
constexpr int kBM = 128;       // rows per block
}

// float -> bf16 (RNE) bit-twiddle — kept only for the tiny prep kernel
__device__ inline unsigned short f2bf(float x) {
    unsigned u = __float_as_uint(x);
    u += 0x7FFFu + ((u >> 16) & 1u);
    return (unsigned short)(u >> 16);
}

// 8x fp32 -> 8x bf16 via v_cvt_pk_bf16_f32 (RNE)
__device__ inline s16x8 pack8(const float4& a, const float4& b) {
    union { s16x8 s; __hip_bfloat162 h[4]; } r;
    r.h[0] = __float22bfloat162_rn(make_float2(a.x, a.y));
    r.h[1] = __float22bfloat162_rn(make_float2(a.z, a.w));
    r.h[2] = __float22bfloat162_rn(make_float2(b.x, b.y));
    r.h[3] = __float22bfloat162_rn(make_float2(b.z, b.w));
    return r.s;
}

// Load 8 consecutive fp32 (16B-aligned) -> bf16x8 A-fragment
__device__ inline s16x8 loadA8(const float* __restrict__ p) {
    const float4* q = reinterpret_cast<const float4*>(p);
    return pack8(q[0], q[1]);
}

// ---------------------------------------------------------------------------
// Prep: W (K,96) fp32 -> WT (96,Kp) bf16, zero-padded K rows. Runs once/call.
// ---------------------------------------------------------------------------
__global__ void prep_wT(const float* __restrict__ Wm, const float* __restrict__ Wu,
                        short* __restrict__ wmT, short* __restrict__ wuT) {
    const int t = blockIdx.x * 256 + threadIdx.x;
    if (t >= 96 * kKp) return;
    const int n = t / kKp, k = t % kKp;
    wmT[t] = (k < 144) ? (short)f2bf(Wm[(size_t)k * 96 + n]) : (short)0;
    wuT[t] = (short)f2bf(Wu[(size_t)k * 96 + n]);
}

// ---------------------------------------------------------------------------
// Shared MFMA GEMM + fp32 bias/ReLU/LN epilogue + store. NO atomics — the
// aggregation is decoupled into scatter_pk (ablation: isolate atomic cost).
// A-frags in registers; B-frags from LDS. C/D: col=lane&15, row=quad*4+reg.
// LN: row lives in one 16-lane quad across 6 N-tiles -> shfl_xor(1,2,4,8).
// ---------------------------------------------------------------------------
__device__ inline void gemm_ln_store(const s16x8 a[5], const short* sB,
                                     const float* __restrict__ bias,
                                     const float* __restrict__ gamma_,
                                     const float* __restrict__ beta_,
                                     float* __restrict__ out,
                                     int rowBase, int rowMax) {
    const int tid  = threadIdx.x;
    const int w    = tid >> 6;
    const int lane = tid & 63;
    const int cl   = lane & 15;
    const int quad = lane >> 4;

    f32x4 acc[6] = {};
#pragma unroll
    for (int ks = 0; ks < 5; ++ks) {
#pragma unroll
        for (int t = 0; t < 6; ++t) {
            s16x8 b = *reinterpret_cast<const s16x8*>(
                sB + (16 * t + cl) * kLd + ks * 32 + quad * 8);
            acc[t] = __builtin_amdgcn_mfma_f32_16x16x32_bf16(a[ks], b, acc[t], 0, 0, 0);
        }
    }

    float bmv[6], gv[6], bv[6];
#pragma unroll
    for (int t = 0; t < 6; ++t) {
        const int c = 16 * t + cl;
        bmv[t] = bias[c]; gv[t] = gamma_[c]; bv[t] = beta_[c];
    }
#pragma unroll
    for (int j = 0; j < 4; ++j) {
        float v0[6];
        float s = 0.f;
#pragma unroll
        for (int t = 0; t < 6; ++t) {
            v0[t] = fmaxf(acc[t][j] + bmv[t], 0.f);
            s += v0[t];
        }
        s += __shfl_xor(s, 1); s += __shfl_xor(s, 2);
        s += __shfl_xor(s, 4); s += __shfl_xor(s, 8);
        const float mu = s * (1.f / 96.f);
        float q = 0.f;
#pragma unroll
        for (int t = 0; t < 6; ++t) {
            const float d = v0[t] - mu;
            q = fmaf(d, d, q);
        }
        q += __shfl_xor(q, 1); q += __shfl_xor(q, 2);
        q += __shfl_xor(q, 4); q += __shfl_xor(q, 8);
        const float inv = rsqrtf(q * (1.f / 96.f) + kEps);
        const int row = rowBase + 16 * w + 4 * quad + j;
        if (row < rowMax) {
            float* orow = out + (size_t)row * kFil;
#pragma unroll
            for (int t = 0; t < 6; ++t)
                orow[16 * t + cl] = (v0[t] - mu) * inv * gv[t] + bv[t];
        }
    }
}

// ---------------------------------------------------------------------------
// Message layer (MFMA): block = 128 edges, 8 waves, each wave owns 16 rows.
// A-fragments loaded directly from global (nodes/efeat are L2/L3-hot).
// ---------------------------------------------------------------------------
__global__ __launch_bounds__(512, 4) void msg_gemm(
    const float* __restrict__ nodes, const float* __restrict__ efeat,
    const int* __restrict__ edges, const short* __restrict__ wmT,
    const float* __restrict__ bm, const float* __restrict__ g,
    const float* __restrict__ be, float* __restrict__ out_msg) {
    __shared__ short sB[96 * kLd];    // 32256 B
    const int tid  = threadIdx.x;
    const int w    = tid >> 6;
    const int lane = tid & 63;
    const int cl   = lane & 15;
    const int quad = lane >> 4;

    const int row = blockIdx.x * kBM + 16 * w + cl;   // 2500*128 = 320000 exact
    const int b   = row / kE;
    const int2 e2 = reinterpret_cast<const int2*>(edges)[row];
    const float* srcp = nodes + ((size_t)b * kN + e2.x) * kF + 8 * quad;
    const float* dstp = nodes + ((size_t)b * kN + e2.y) * kF + 8 * quad;

    s16x8 a[5];
    a[0] = loadA8(srcp);           // k =   0+8q+j
    a[1] = loadA8(srcp + 32);      // k =  32+8q+j
    a[2] = loadA8(dstp);           // k =  64+8q+j
    a[3] = loadA8(dstp + 32);      // k =  96+8q+j
    if (quad < 2) {
        a[4] = loadA8(efeat + (size_t)row * kFE + 8 * quad);  // k = 128..143
    } else {
        s16x8 z = {};
        a[4] = z;                  // zero-pad K 144..159
    }

    for (int i = tid; i < 96 * kKp / 8; i += 512) {   // 1920 16B chunks
        const int n = i / 20, c = i % 20;
        *reinterpret_cast<s16x8*>(sB + n * kLd + 8 * c) =
            *reinterpret_cast<const s16x8*>(wmT + n * kKp + 8 * c);
    }
    __syncthreads();
    gemm_ln_store(a, sB, bm, g, be, out_msg, blockIdx.x * kBM, kBE);
}

// ---------------------------------------------------------------------------
// Scatter: decoupled segment-sum via pk-bf16 atomics. Thread = (edge, pair):
// 48 threads cover one edge's 96 cols. Reads out_msg fully coalesced
// (L3-hot, just written); one contiguous pk-atomic per thread — the 48
// dwords of an edge are contiguous (192 B = sector-friendly, r5 lesson).
// 15.36M threads = 240K waves -> atomic latency pipelined by sheer TLP.
// ---------------------------------------------------------------------------
__global__ __launch_bounds__(256) void scatter_pk(
    const float* __restrict__ out_msg, const int* __restrict__ edges,
    short* __restrict__ agg) {
    const int idx  = blockIdx.x * 256 + threadIdx.x;   // 60000 blocks exact
    const int edge = idx / 48;                         // magic-mul div
    const int pair = idx - edge * 48;
    const int b    = edge / kE;
    const int dn   = edges[(size_t)edge * 2 + 1];      // 48 threads share row
    const float2 v = reinterpret_cast<const float2*>(
        out_msg + (size_t)edge * kFil)[pair];
    __hip_bfloat162 hv = __float22bfloat162_rn(make_float2(v.x, v.y));
    unsigned dw;
    __builtin_memcpy(&dw, &hv, 4);
    short* addr = agg + ((size_t)b * kN + dn) * kFil + 2 * pair;
    asm volatile("global_atomic_pk_add_bf16 %0, %1, off"
                 :: "v"((unsigned long long)addr), "v"(dw) : "memory");
}

// ---------------------------------------------------------------------------
// Update layer (MFMA): block = 128 nodes; X row = [node(64)|agg(96)], K=160.
// agg is bf16 -> A-fragments for k>=64 are direct 16B loads (no convert).
// ---------------------------------------------------------------------------
__global__ __launch_bounds__(512, 4) void upd_mfma(
    const float* __restrict__ nodes, const short* __restrict__ agg,
    const short* __restrict__ wuT, const float* __restrict__ bu,
    const float* __restrict__ g, const float* __restrict__ be,
    float* __restrict__ out_upd) {
    __shared__ short sB[96 * kLd];
    const int tid  = threadIdx.x;
    const int w    = tid >> 6;
    const int lane = tid & 63;
    const int cl   = lane & 15;
    const int quad = lane >> 4;

    const int node0 = blockIdx.x * kBM + 16 * w + cl;
    const int node  = (node0 < kBN) ? node0 : (kBN - 1);  // clamp loads; store guarded
    const float* np = nodes + (size_t)node * kF + 8 * quad;
    const short* ap = agg + (size_t)node * kFil;

    s16x8 a[5];
    a[0] = loadA8(np);                 // k =   0+8q+j -> node[ 0+8q..]
    a[1] = loadA8(np + 32);            // k =  32+8q+j -> node[32+8q..]
    a[2] = *reinterpret_cast<const s16x8*>(ap + 8 * quad);       // agg[ 0+8q..]
    a[3] = *reinterpret_cast<const s16x8*>(ap + 32 + 8 * quad);  // agg[32+8q..]
    a[4] = *reinterpret_cast<const s16x8*>(ap + 64 + 8 * quad);  // agg[64+8q..]

    for (int i = tid; i < 96 * kKp / 8; i += 512) {
        const int n = i / 20, c = i % 20;
        *reinterpret_cast<s16x8*>(sB + n * kLd + 8 * c) =
            *reinterpret_cast<const s16x8*>(wuT + n * kKp + 8 * c);
    }
    __syncthreads();
    gemm_ln_store(a, sB, bu, g, be, out_upd, blockIdx.x * kBM, kBN);
}

extern "C" void kernel_launch(void* const* d_in, const int* in_sizes, int n_in,
                              void* d_out, int out_size, void* d_ws, size_t ws_size,
                              hipStream_t stream) {
    const float* nodes  = (const float*)d_in[0];
    const float* efeat  = (const float*)d_in[1];
    const int*   edges  = (const int*)d_in[2];
    const float* Wm     = (const float*)d_in[3];
    const float* bm     = (const float*)d_in[4];
    const float* ln_m_g = (const float*)d_in[5];
    const float* ln_m_b = (const float*)d_in[6];
    const float* Wu     = (const float*)d_in[7];
    const float* bu     = (const float*)d_in[8];
    const float* ln_u_g = (const float*)d_in[9];
    const float* ln_u_b = (const float*)d_in[10];

    float* out_upd = (float*)d_out;                           // (B,N,96) first
    float* out_msg = (float*)d_out + (size_t)kBN * kFil;      // (B,E,96) second

    // workspace layout; 16B-aligned segments
    short* wmT = (short*)d_ws;                                // 96*160 bf16
    short* wuT = wmT + 96 * kKp;                              // 96*160 bf16
    short* agg = wuT + 96 * kKp;                              // B*N*96 bf16 (7.7 MB)

    // zero the aggregation buffer (atomic accumulation target)
    hipMemsetAsync(agg, 0, (size_t)kBN * kFil * sizeof(short), stream);
    prep_wT<<<(96 * kKp + 255) / 256, 256, 0, stream>>>(Wm, Wu, wmT, wuT);

    msg_gemm<<<kBE / kBM, 512, 0, stream>>>(
        nodes, efeat, edges, wmT, bm, ln_m_g, ln_m_b, out_msg);
    scatter_pk<<<kBE * 48 / 256, 256, 0, stream>>>(out_msg, edges, agg);
    upd_mfma<<<(kBN + kBM - 1) / kBM, 512, 0, stream>>>(
        nodes, agg, wuT, bu, ln_u_g, ln_u_b, out_upd);
}

// Round 8
// 271.994 us; speedup vs baseline: 2.9158x; 1.0147x over previous
//
#include <hip/hip_runtime.h>
#include <hip/hip_bf16.h>

typedef short s16x8 __attribute__((ext_vector_type(8)));
typedef float f32x4 __attribute__((ext_vector_type(4)));

namespace {
constexpr int kB   = 8;
constexpr int kN   = 5000;
constexpr int kE   = 40000;
constexpr int kF   = 64;
constexpr int kFE  = 16;
constexpr int kFil = 96;
constexpr float kEps = 1e-3f;
constexpr int kBN = kB * kN;   // 40000
constexpr int kBE = kB * kE;   // 320000
constexpr int kKp = 160;       // padded K (msg 144->160, upd exact 160)
constexpr int kLd = 168;       // LDS row stride in bf16 elems (r3-proven)
constexpr int kBM = 128;       // rows per block (upd)
constexpr int kBM2 = 256;      // rows per block (msg: 2 tiles/wave, shared B)
}

// float -> bf16 (RNE) bit-twiddle — kept only for the tiny prep kernel
__device__ inline unsigned short f2bf(float x) {
    unsigned u = __float_as_uint(x);
    u += 0x7FFFu + ((u >> 16) & 1u);
    return (unsigned short)(u >> 16);
}

// 8x fp32 -> 8x bf16 via v_cvt_pk_bf16_f32 (RNE)
__device__ inline s16x8 pack8(const float4& a, const float4& b) {
    union { s16x8 s; __hip_bfloat162 h[4]; } r;
    r.h[0] = __float22bfloat162_rn(make_float2(a.x, a.y));
    r.h[1] = __float22bfloat162_rn(make_float2(a.z, a.w));
    r.h[2] = __float22bfloat162_rn(make_float2(b.x, b.y));
    r.h[3] = __float22bfloat162_rn(make_float2(b.z, b.w));
    return r.s;
}

// Load 8 consecutive fp32 (16B-aligned) -> bf16x8 A-fragment
__device__ inline s16x8 loadA8(const float* __restrict__ p) {
    const float4* q = reinterpret_cast<const float4*>(p);
    return pack8(q[0], q[1]);
}

// ---------------------------------------------------------------------------
// Prep + zero: W (K,96) fp32 -> WT (96,Kp) bf16 (first 60 blocks) AND zero
// the bf16 agg buffer (all 1875 blocks). Replaces prep_wT + hipMemsetAsync.
// ---------------------------------------------------------------------------
__global__ __launch_bounds__(256) void prep_zero(
    const float* __restrict__ Wm, const float* __restrict__ Wu,
    short* __restrict__ wmT, short* __restrict__ wuT,
    s16x8* __restrict__ aggz) {
    const int t = blockIdx.x * 256 + threadIdx.x;
    if (t < 96 * kKp) {
        const int n = t / kKp, k = t % kKp;
        wmT[t] = (k < 144) ? (short)f2bf(Wm[(size_t)k * 96 + n]) : (short)0;
        wuT[t] = (short)f2bf(Wu[(size_t)k * 96 + n]);
    }
    if (t < kBN * kFil / 8) {          // 480000 16B chunks
        s16x8 z = {};
        aggz[t] = z;
    }
}

// ---------------------------------------------------------------------------
// bias/ReLU/LN epilogue + paired float2 store for one 16-row output tile
// group. acc layout: col=16t+cl, row=row0+j (row0 = base+16w+4quad).
// LN: a row's 96 cols live in one 16-lane quad across 6 N-tiles ->
// shfl_xor(1,2,4,8). Stores: lane pair (cl,cl^1) merges into one float2
// (12 store instrs instead of 24).
// ---------------------------------------------------------------------------
__device__ inline void ln_epilogue(const f32x4 acc[6],
                                   const float bmv[6], const float gv[6],
                                   const float bv[6],
                                   float* __restrict__ out,
                                   int row0, int cl, int rowMax) {
#pragma unroll
    for (int j = 0; j < 4; ++j) {
        float v0[6];
        float s = 0.f;
#pragma unroll
        for (int t = 0; t < 6; ++t) {
            v0[t] = fmaxf(acc[t][j] + bmv[t], 0.f);
            s += v0[t];
        }
        s += __shfl_xor(s, 1); s += __shfl_xor(s, 2);
        s += __shfl_xor(s, 4); s += __shfl_xor(s, 8);
        const float mu = s * (1.f / 96.f);
        float q = 0.f;
#pragma unroll
        for (int t = 0; t < 6; ++t) {
            const float d = v0[t] - mu;
            q = fmaf(d, d, q);
        }
        q += __shfl_xor(q, 1); q += __shfl_xor(q, 2);
        q += __shfl_xor(q, 4); q += __shfl_xor(q, 8);
        const float inv = rsqrtf(q * (1.f / 96.f) + kEps);
        const int row = row0 + j;
        if (row < rowMax) {
            float* orow = out + (size_t)row * kFil;
            float ov[6];
#pragma unroll
            for (int t = 0; t < 6; ++t)
                ov[t] = (v0[t] - mu) * inv * gv[t] + bv[t];
#pragma unroll
            for (int t = 0; t < 6; ++t) {
                const float other = __shfl_xor(ov[t], 1);   // partner col
                if ((cl & 1) == 0) {
                    float2 st; st.x = ov[t]; st.y = other;
                    *reinterpret_cast<float2*>(orow + 16 * t + cl) = st;
                }
            }
        }
    }
}

// ---------------------------------------------------------------------------
// Message layer (MFMA): block = 256 edges, 8 waves; each wave owns TWO
// 16-row tiles (rA0, rA0+128) sharing every B-fragment ds_read (2 MFMAs per
// LDS read). A-fragments loaded directly from global (nodes/efeat L2-hot);
// 10 A-loads in flight per lane hides gather latency. No atomics (split).
// ---------------------------------------------------------------------------
__global__ __launch_bounds__(512) void msg_gemm(
    const float* __restrict__ nodes, const float* __restrict__ efeat,
    const int* __restrict__ edges, const short* __restrict__ wmT,
    const float* __restrict__ bm, const float* __restrict__ g,
    const float* __restrict__ be, float* __restrict__ out_msg) {
    __shared__ short sB[96 * kLd];    // 32256 B
    const int tid  = threadIdx.x;
    const int w    = tid >> 6;
    const int lane = tid & 63;
    const int cl   = lane & 15;
    const int quad = lane >> 4;

    const int rA0 = blockIdx.x * kBM2 + 16 * w + cl;   // 1250*256 = 320000 exact
    const int rA1 = rA0 + 128;
    const int b0  = rA0 / kE;
    const int b1  = rA1 / kE;
    const int2 e0 = reinterpret_cast<const int2*>(edges)[rA0];
    const int2 e1 = reinterpret_cast<const int2*>(edges)[rA1];
    const float* s0p = nodes + ((size_t)b0 * kN + e0.x) * kF + 8 * quad;
    const float* d0p = nodes + ((size_t)b0 * kN + e0.y) * kF + 8 * quad;
    const float* s1p = nodes + ((size_t)b1 * kN + e1.x) * kF + 8 * quad;
    const float* d1p = nodes + ((size_t)b1 * kN + e1.y) * kF + 8 * quad;

    s16x8 a0[5], a1[5];
    a0[0] = loadA8(s0p);       a1[0] = loadA8(s1p);
    a0[1] = loadA8(s0p + 32);  a1[1] = loadA8(s1p + 32);
    a0[2] = loadA8(d0p);       a1[2] = loadA8(d1p);
    a0[3] = loadA8(d0p + 32);  a1[3] = loadA8(d1p + 32);
    if (quad < 2) {
        a0[4] = loadA8(efeat + (size_t)rA0 * kFE + 8 * quad);
        a1[4] = loadA8(efeat + (size_t)rA1 * kFE + 8 * quad);
    } else {
        s16x8 z = {};
        a0[4] = z; a1[4] = z;          // zero-pad K 144..159
    }

    for (int i = tid; i < 96 * kKp / 8; i += 512) {   // 1920 16B chunks
        const int n = i / 20, c = i % 20;
        *reinterpret_cast<s16x8*>(sB + n * kLd + 8 * c) =
            *reinterpret_cast<const s16x8*>(wmT + n * kKp + 8 * c);
    }
    __syncthreads();

    f32x4 acc0[6] = {}, acc1[6] = {};
#pragma unroll
    for (int ks = 0; ks < 5; ++ks) {
#pragma unroll
        for (int t = 0; t < 6; ++t) {
            s16x8 bfr = *reinterpret_cast<const s16x8*>(
                sB + (16 * t + cl) * kLd + ks * 32 + quad * 8);
            acc0[t] = __builtin_amdgcn_mfma_f32_16x16x32_bf16(a0[ks], bfr, acc0[t], 0, 0, 0);
            acc1[t] = __builtin_amdgcn_mfma_f32_16x16x32_bf16(a1[ks], bfr, acc1[t], 0, 0, 0);
        }
    }

    float bmv[6], gv[6], bv[6];
#pragma unroll
    for (int t = 0; t < 6; ++t) {
        const int c = 16 * t + cl;
        bmv[t] = bm[c]; gv[t] = g[c]; bv[t] = be[c];
    }
    const int row0 = blockIdx.x * kBM2 + 16 * w + 4 * quad;
    ln_epilogue(acc0, bmv, gv, bv, out_msg, row0,       cl, kBE);
    ln_epilogue(acc1, bmv, gv, bv, out_msg, row0 + 128, cl, kBE);
}

// ---------------------------------------------------------------------------
// Scatter: decoupled segment-sum via pk-bf16 atomics (r6-proven). Thread =
// (edge, pair); 48 threads cover one edge's 96 cols, contiguous 192 B per
// edge (sector-friendly — r5 lesson). 240K waves pipeline atomic latency.
// ---------------------------------------------------------------------------
__global__ __launch_bounds__(256) void scatter_pk(
    const float* __restrict__ out_msg, const int* __restrict__ edges,
    short* __restrict__ agg) {
    const int idx  = blockIdx.x * 256 + threadIdx.x;   // 60000 blocks exact
    const int edge = idx / 48;                         // magic-mul div
    const int pair = idx - edge * 48;
    const int b    = edge / kE;
    const int dn   = edges[(size_t)edge * 2 + 1];      // 48 threads share row
    const float2 v = reinterpret_cast<const float2*>(
        out_msg + (size_t)edge * kFil)[pair];
    __hip_bfloat162 hv = __float22bfloat162_rn(make_float2(v.x, v.y));
    unsigned dw;
    __builtin_memcpy(&dw, &hv, 4);
    short* addr = agg + ((size_t)b * kN + dn) * kFil + 2 * pair;
    asm volatile("global_atomic_pk_add_bf16 %0, %1, off"
                 :: "v"((unsigned long long)addr), "v"(dw) : "memory");
}

// ---------------------------------------------------------------------------
// Update layer (MFMA): block = 128 nodes; X row = [node(64)|agg(96)], K=160.
// agg is bf16 -> A-fragments for k>=64 are direct 16B loads (no convert).
// ---------------------------------------------------------------------------
__global__ __launch_bounds__(512, 4) void upd_mfma(
    const float* __restrict__ nodes, const short* __restrict__ agg,
    const short* __restrict__ wuT, const float* __restrict__ bu,
    const float* __restrict__ g, const float* __restrict__ be,
    float* __restrict__ out_upd) {
    __shared__ short sB[96 * kLd];
    const int tid  = threadIdx.x;
    const int w    = tid >> 6;
    const int lane = tid & 63;
    const int cl   = lane & 15;
    const int quad = lane >> 4;

    const int node0 = blockIdx.x * kBM + 16 * w + cl;
    const int node  = (node0 < kBN) ? node0 : (kBN - 1);  // clamp loads; store guarded
    const float* np = nodes + (size_t)node * kF + 8 * quad;
    const short* ap = agg + (size_t)node * kFil;

    s16x8 a[5];
    a[0] = loadA8(np);                 // k =   0+8q+j -> node[ 0+8q..]
    a[1] = loadA8(np + 32);            // k =  32+8q+j -> node[32+8q..]
    a[2] = *reinterpret_cast<const s16x8*>(ap + 8 * quad);       // agg[ 0+8q..]
    a[3] = *reinterpret_cast<const s16x8*>(ap + 32 + 8 * quad);  // agg[32+8q..]
    a[4] = *reinterpret_cast<const s16x8*>(ap + 64 + 8 * quad);  // agg[64+8q..]

    for (int i = tid; i < 96 * kKp / 8; i += 512) {
        const int n = i / 20, c = i % 20;
        *reinterpret_cast<s16x8*>(sB + n * kLd + 8 * c) =
            *reinterpret_cast<const s16x8*>(wuT + n * kKp + 8 * c);
    }
    __syncthreads();

    f32x4 acc[6] = {};
#pragma unroll
    for (int ks = 0; ks < 5; ++ks) {
#pragma unroll
        for (int t = 0; t < 6; ++t) {
            s16x8 bfr = *reinterpret_cast<const s16x8*>(
                sB + (16 * t + cl) * kLd + ks * 32 + quad * 8);
            acc[t] = __builtin_amdgcn_mfma_f32_16x16x32_bf16(a[ks], bfr, acc[t], 0, 0, 0);
        }
    }

    float bmv[6], gv[6], bv[6];
#pragma unroll
    for (int t = 0; t < 6; ++t) {
        const int c = 16 * t + cl;
        bmv[t] = bu[c]; gv[t] = g[c]; bv[t] = be[c];
    }
    ln_epilogue(acc, bmv, gv, bv, out_upd,
                blockIdx.x * kBM + 16 * w + 4 * quad, cl, kBN);
}

extern "C" void kernel_launch(void* const* d_in, const int* in_sizes, int n_in,
                              void* d_out, int out_size, void* d_ws, size_t ws_size,
                              hipStream_t stream) {
    const float* nodes  = (const float*)d_in[0];
    const float* efeat  = (const float*)d_in[1];
    const int*   edges  = (const int*)d_in[2];
    const float* Wm     = (const float*)d_in[3];
    const float* bm     = (const float*)d_in[4];
    const float* ln_m_g = (const float*)d_in[5];
    const float* ln_m_b = (const float*)d_in[6];
    const float* Wu     = (const float*)d_in[7];
    const float* bu     = (const float*)d_in[8];
    const float* ln_u_g = (const float*)d_in[9];
    const float* ln_u_b = (const float*)d_in[10];

    float* out_upd = (float*)d_out;                           // (B,N,96) first
    float* out_msg = (float*)d_out + (size_t)kBN * kFil;      // (B,E,96) second

    // workspace layout; 16B-aligned segments
    short* wmT = (short*)d_ws;                                // 96*160 bf16
    short* wuT = wmT + 96 * kKp;                              // 96*160 bf16
    short* agg = wuT + 96 * kKp;                              // B*N*96 bf16 (7.7 MB)

    // prep weights + zero agg in one dispatch (480000 16B chunks)
    prep_zero<<<(kBN * kFil / 8 + 255) / 256, 256, 0, stream>>>(
        Wm, Wu, wmT, wuT, (s16x8*)agg);

    msg_gemm<<<kBE / kBM2, 512, 0, stream>>>(
        nodes, efeat, edges, wmT, bm, ln_m_g, ln_m_b, out_msg);
    scatter_pk<<<kBE * 48 / 256, 256, 0, stream>>>(out_msg, edges, agg);
    upd_mfma<<<(kBN + kBM - 1) / kBM, 512, 0, stream>>>(
        nodes, agg, wuT, bu, ln_u_g, ln_u_b, out_upd);
}

// Round 9
// 268.857 us; speedup vs baseline: 2.9498x; 1.0117x over previous
//
#include <hip/hip_runtime.h>
#include <hip/hip_bf16.h>

typedef short s16x8 __attribute__((ext_vector_type(8)));
typedef float f32x4 __attribute__((ext_vector_type(4)));

namespace {
constexpr int kB   = 8;
constexpr int kN   = 5000;
constexpr int kE   = 40000;
constexpr int kF   = 64;
constexpr int kFE  = 16;
constexpr int kFil = 96;
constexpr float kEps = 1e-3f;
constexpr int kBN = kB * kN;   // 40000
constexpr int kBE = kB * kE;   // 320000
constexpr int kKp = 160;       // padded K (msg 144->160, upd exact 160)
constexpr int kLd = 168;       // LDS row stride in bf16 elems (r3-proven)
constexpr int kBM = 128;       // rows per block (upd)
constexpr int kBM2 = 256;      // rows per block (msg: 2 tiles/wave, shared B)
constexpr int kZChunks = kBN * kFil / 8;          // 480000 16B agg chunks
constexpr int kZPerBlk = kZChunks / (kBE / kBM2); // 384 per msg block
}

// float -> bf16 (RNE) bit-twiddle — kept only for the tiny prep kernel
__device__ inline unsigned short f2bf(float x) {
    unsigned u = __float_as_uint(x);
    u += 0x7FFFu + ((u >> 16) & 1u);
    return (unsigned short)(u >> 16);
}

// 8x fp32 -> 8x bf16 via v_cvt_pk_bf16_f32 (RNE)
__device__ inline s16x8 pack8(const float4& a, const float4& b) {
    union { s16x8 s; __hip_bfloat162 h[4]; } r;
    r.h[0] = __float22bfloat162_rn(make_float2(a.x, a.y));
    r.h[1] = __float22bfloat162_rn(make_float2(a.z, a.w));
    r.h[2] = __float22bfloat162_rn(make_float2(b.x, b.y));
    r.h[3] = __float22bfloat162_rn(make_float2(b.z, b.w));
    return r.s;
}

// Load 8 consecutive fp32 (16B-aligned) -> bf16x8 A-fragment
__device__ inline s16x8 loadA8(const float* __restrict__ p) {
    const float4* q = reinterpret_cast<const float4*>(p);
    return pack8(q[0], q[1]);
}

// ---------------------------------------------------------------------------
// DPP cross-lane helpers (16-lane-row scope) — replace __shfl_xor's LDS
// ds_swizzle round-trip with a single VALU DPP op. Reductions here are
// strictly within each 16-lane row (cl group), exactly DPP's row domain.
// quad_perm [1,0,3,2]=0xB1 (xor1), [2,3,0,1]=0x4E (xor2),
// row_ror:4=0x124, row_ror:8=0x128 (rotations compose to a full row sum).
// ---------------------------------------------------------------------------
template <int CTRL>
__device__ inline float dpp_mov(float x) {
    return __int_as_float(__builtin_amdgcn_update_dpp(
        0, __float_as_int(x), CTRL, 0xF, 0xF, true));
}
__device__ inline float row16_sum(float s) {
    s += dpp_mov<0xB1>(s);    // + xor1
    s += dpp_mov<0x4E>(s);    // + xor2  -> quad sums
    s += dpp_mov<0x124>(s);   // + ror4
    s += dpp_mov<0x128>(s);   // + ror8  -> full 16-lane sum in every lane
    return s;
}

// ---------------------------------------------------------------------------
// Prep: W (K,96) fp32 -> WT (96,Kp) bf16, zero-padded K rows. 60 blocks.
// (agg zeroing moved into msg_gemm's latency slack.)
// ---------------------------------------------------------------------------
__global__ __launch_bounds__(256) void prep_wT(
    const float* __restrict__ Wm, const float* __restrict__ Wu,
    short* __restrict__ wmT, short* __restrict__ wuT) {
    const int t = blockIdx.x * 256 + threadIdx.x;
    if (t >= 96 * kKp) return;
    const int n = t / kKp, k = t % kKp;
    wmT[t] = (k < 144) ? (short)f2bf(Wm[(size_t)k * 96 + n]) : (short)0;
    wuT[t] = (short)f2bf(Wu[(size_t)k * 96 + n]);
}

// ---------------------------------------------------------------------------
// bias/ReLU/LN epilogue + paired float2 store for one 16-row output tile
// group. acc layout: col=16t+cl, row=row0+j. LN reductions + store pairing
// all via DPP (zero LDS traffic in the epilogue).
// ---------------------------------------------------------------------------
__device__ inline void ln_epilogue(const f32x4 acc[6],
                                   const float bmv[6], const float gv[6],
                                   const float bv[6],
                                   float* __restrict__ out,
                                   int row0, int cl, int rowMax) {
#pragma unroll
    for (int j = 0; j < 4; ++j) {
        float v0[6];
        float s = 0.f;
#pragma unroll
        for (int t = 0; t < 6; ++t) {
            v0[t] = fmaxf(acc[t][j] + bmv[t], 0.f);
            s += v0[t];
        }
        s = row16_sum(s);
        const float mu = s * (1.f / 96.f);
        float q = 0.f;
#pragma unroll
        for (int t = 0; t < 6; ++t) {
            const float d = v0[t] - mu;
            q = fmaf(d, d, q);
        }
        q = row16_sum(q);
        const float inv = rsqrtf(q * (1.f / 96.f) + kEps);
        const int row = row0 + j;
        if (row < rowMax) {
            float* orow = out + (size_t)row * kFil;
            float ov[6];
#pragma unroll
            for (int t = 0; t < 6; ++t)
                ov[t] = (v0[t] - mu) * inv * gv[t] + bv[t];
#pragma unroll
            for (int t = 0; t < 6; ++t) {
                const float other = dpp_mov<0xB1>(ov[t]);   // partner col (xor1)
                if ((cl & 1) == 0) {
                    float2 st; st.x = ov[t]; st.y = other;
                    *reinterpret_cast<float2*>(orow + 16 * t + cl) = st;
                }
            }
        }
    }
}

// ---------------------------------------------------------------------------
// Message layer (MFMA): block = 256 edges, 8 waves; each wave owns TWO
// 16-row tiles (rA0, rA0+128) sharing every B-fragment ds_read (2 MFMAs per
// LDS read). A-fragments loaded directly from global (nodes/efeat L2-hot).
// Also zeroes its 6.3 KB slice of agg (ordered before scatter by the
// kernel boundary; overlaps the gather latency).
// ---------------------------------------------------------------------------
__global__ __launch_bounds__(512) void msg_gemm(
    const float* __restrict__ nodes, const float* __restrict__ efeat,
    const int* __restrict__ edges, const short* __restrict__ wmT,
    const float* __restrict__ bm, const float* __restrict__ g,
    const float* __restrict__ be, float* __restrict__ out_msg,
    s16x8* __restrict__ aggz) {
    __shared__ short sB[96 * kLd];    // 32256 B
    const int tid  = threadIdx.x;
    const int w    = tid >> 6;
    const int lane = tid & 63;
    const int cl   = lane & 15;
    const int quad = lane >> 4;

    const int rA0 = blockIdx.x * kBM2 + 16 * w + cl;   // 1250*256 = 320000 exact
    const int rA1 = rA0 + 128;
    const int b0  = rA0 / kE;
    const int b1  = rA1 / kE;
    const int2 e0 = reinterpret_cast<const int2*>(edges)[rA0];
    const int2 e1 = reinterpret_cast<const int2*>(edges)[rA1];
    const float* s0p = nodes + ((size_t)b0 * kN + e0.x) * kF + 8 * quad;
    const float* d0p = nodes + ((size_t)b0 * kN + e0.y) * kF + 8 * quad;
    const float* s1p = nodes + ((size_t)b1 * kN + e1.x) * kF + 8 * quad;
    const float* d1p = nodes + ((size_t)b1 * kN + e1.y) * kF + 8 * quad;

    s16x8 a0[5], a1[5];
    a0[0] = loadA8(s0p);       a1[0] = loadA8(s1p);
    a0[1] = loadA8(s0p + 32);  a1[1] = loadA8(s1p + 32);
    a0[2] = loadA8(d0p);       a1[2] = loadA8(d1p);
    a0[3] = loadA8(d0p + 32);  a1[3] = loadA8(d1p + 32);
    if (quad < 2) {
        a0[4] = loadA8(efeat + (size_t)rA0 * kFE + 8 * quad);
        a1[4] = loadA8(efeat + (size_t)rA1 * kFE + 8 * quad);
    } else {
        s16x8 z = {};
        a0[4] = z; a1[4] = z;          // zero-pad K 144..159
    }

    // zero this block's agg slice (384 16B chunks; threads 0..383)
    if (tid < kZPerBlk) {
        s16x8 z = {};
        aggz[(size_t)blockIdx.x * kZPerBlk + tid] = z;
    }

    for (int i = tid; i < 96 * kKp / 8; i += 512) {   // 1920 16B chunks
        const int n = i / 20, c = i % 20;
        *reinterpret_cast<s16x8*>(sB + n * kLd + 8 * c) =
            *reinterpret_cast<const s16x8*>(wmT + n * kKp + 8 * c);
    }
    __syncthreads();

    f32x4 acc0[6] = {}, acc1[6] = {};
#pragma unroll
    for (int ks = 0; ks < 5; ++ks) {
#pragma unroll
        for (int t = 0; t < 6; ++t) {
            s16x8 bfr = *reinterpret_cast<const s16x8*>(
                sB + (16 * t + cl) * kLd + ks * 32 + quad * 8);
            acc0[t] = __builtin_amdgcn_mfma_f32_16x16x32_bf16(a0[ks], bfr, acc0[t], 0, 0, 0);
            acc1[t] = __builtin_amdgcn_mfma_f32_16x16x32_bf16(a1[ks], bfr, acc1[t], 0, 0, 0);
        }
    }

    float bmv[6], gv[6], bv[6];
#pragma unroll
    for (int t = 0; t < 6; ++t) {
        const int c = 16 * t + cl;
        bmv[t] = bm[c]; gv[t] = g[c]; bv[t] = be[c];
    }
    const int row0 = blockIdx.x * kBM2 + 16 * w + 4 * quad;
    ln_epilogue(acc0, bmv, gv, bv, out_msg, row0,       cl, kBE);
    ln_epilogue(acc1, bmv, gv, bv, out_msg, row0 + 128, cl, kBE);
}

// ---------------------------------------------------------------------------
// Scatter: decoupled segment-sum via pk-bf16 atomics (r6-proven). Thread =
// (edge, pair); 48 threads cover one edge's 96 cols, contiguous 192 B per
// edge (sector-friendly — r5 lesson). 240K waves pipeline atomic latency.
// ---------------------------------------------------------------------------
__global__ __launch_bounds__(256) void scatter_pk(
    const float* __restrict__ out_msg, const int* __restrict__ edges,
    short* __restrict__ agg) {
    const int idx  = blockIdx.x * 256 + threadIdx.x;   // 60000 blocks exact
    const int edge = idx / 48;                         // magic-mul div
    const int pair = idx - edge * 48;
    const int b    = edge / kE;
    const int dn   = edges[(size_t)edge * 2 + 1];      // 48 threads share row
    const float2 v = reinterpret_cast<const float2*>(
        out_msg + (size_t)edge * kFil)[pair];
    __hip_bfloat162 hv = __float22bfloat162_rn(make_float2(v.x, v.y));
    unsigned dw;
    __builtin_memcpy(&dw, &hv, 4);
    short* addr = agg + ((size_t)b * kN + dn) * kFil + 2 * pair;
    asm volatile("global_atomic_pk_add_bf16 %0, %1, off"
                 :: "v"((unsigned long long)addr), "v"(dw) : "memory");
}

// ---------------------------------------------------------------------------
// Update layer (MFMA): block = 128 nodes; X row = [node(64)|agg(96)], K=160.
// agg is bf16 -> A-fragments for k>=64 are direct 16B loads (no convert).
// ---------------------------------------------------------------------------
__global__ __launch_bounds__(512, 4) void upd_mfma(
    const float* __restrict__ nodes, const short* __restrict__ agg,
    const short* __restrict__ wuT, const float* __restrict__ bu,
    const float* __restrict__ g, const float* __restrict__ be,
    float* __restrict__ out_upd) {
    __shared__ short sB[96 * kLd];
    const int tid  = threadIdx.x;
    const int w    = tid >> 6;
    const int lane = tid & 63;
    const int cl   = lane & 15;
    const int quad = lane >> 4;

    const int node0 = blockIdx.x * kBM + 16 * w + cl;
    const int node  = (node0 < kBN) ? node0 : (kBN - 1);  // clamp loads; store guarded
    const float* np = nodes + (size_t)node * kF + 8 * quad;
    const short* ap = agg + (size_t)node * kFil;

    s16x8 a[5];
    a[0] = loadA8(np);                 // k =   0+8q+j -> node[ 0+8q..]
    a[1] = loadA8(np + 32);            // k =  32+8q+j -> node[32+8q..]
    a[2] = *reinterpret_cast<const s16x8*>(ap + 8 * quad);       // agg[ 0+8q..]
    a[3] = *reinterpret_cast<const s16x8*>(ap + 32 + 8 * quad);  // agg[32+8q..]
    a[4] = *reinterpret_cast<const s16x8*>(ap + 64 + 8 * quad);  // agg[64+8q..]

    for (int i = tid; i < 96 * kKp / 8; i += 512) {
        const int n = i / 20, c = i % 20;
        *reinterpret_cast<s16x8*>(sB + n * kLd + 8 * c) =
            *reinterpret_cast<const s16x8*>(wuT + n * kKp + 8 * c);
    }
    __syncthreads();

    f32x4 acc[6] = {};
#pragma unroll
    for (int ks = 0; ks < 5; ++ks) {
#pragma unroll
        for (int t = 0; t < 6; ++t) {
            s16x8 bfr = *reinterpret_cast<const s16x8*>(
                sB + (16 * t + cl) * kLd + ks * 32 + quad * 8);
            acc[t] = __builtin_amdgcn_mfma_f32_16x16x32_bf16(a[ks], bfr, acc[t], 0, 0, 0);
        }
    }

    float bmv[6], gv[6], bv[6];
#pragma unroll
    for (int t = 0; t < 6; ++t) {
        const int c = 16 * t + cl;
        bmv[t] = bu[c]; gv[t] = g[c]; bv[t] = be[c];
    }
    ln_epilogue(acc, bmv, gv, bv, out_upd,
                blockIdx.x * kBM + 16 * w + 4 * quad, cl, kBN);
}

extern "C" void kernel_launch(void* const* d_in, const int* in_sizes, int n_in,
                              void* d_out, int out_size, void* d_ws, size_t ws_size,
                              hipStream_t stream) {
    const float* nodes  = (const float*)d_in[0];
    const float* efeat  = (const float*)d_in[1];
    const int*   edges  = (const int*)d_in[2];
    const float* Wm     = (const float*)d_in[3];
    const float* bm     = (const float*)d_in[4];
    const float* ln_m_g = (const float*)d_in[5];
    const float* ln_m_b = (const float*)d_in[6];
    const float* Wu     = (const float*)d_in[7];
    const float* bu     = (const float*)d_in[8];
    const float* ln_u_g = (const float*)d_in[9];
    const float* ln_u_b = (const float*)d_in[10];

    float* out_upd = (float*)d_out;                           // (B,N,96) first
    float* out_msg = (float*)d_out + (size_t)kBN * kFil;      // (B,E,96) second

    // workspace layout; 16B-aligned segments
    short* wmT = (short*)d_ws;                                // 96*160 bf16
    short* wuT = wmT + 96 * kKp;                              // 96*160 bf16
    short* agg = wuT + 96 * kKp;                              // B*N*96 bf16 (7.7 MB)

    prep_wT<<<(96 * kKp + 255) / 256, 256, 0, stream>>>(Wm, Wu, wmT, wuT);

    msg_gemm<<<kBE / kBM2, 512, 0, stream>>>(
        nodes, efeat, edges, wmT, bm, ln_m_g, ln_m_b, out_msg, (s16x8*)agg);
    scatter_pk<<<kBE * 48 / 256, 256, 0, stream>>>(out_msg, edges, agg);
    upd_mfma<<<(kBN + kBM - 1) / kBM, 512, 0, stream>>>(
        nodes, agg, wuT, bu, ln_u_g, ln_u_b, out_upd);
}